// Round 3
// baseline (1284.056 us; speedup 1.0000x reference)
//
#include <hip/hip_runtime.h>
#include <math.h>

#define N_NODES 661
#define N_GRAPH 128
#define DEG 8
#define EPG (N_NODES*DEG)          // 5288 edges per graph per matrix
#define NTOT (N_NODES*N_GRAPH)     // 84608 nodes
#define FDIM 64
#define NF ((size_t)NTOT*FDIM)     // elements per [n,64] array
#define OSTR 672                   // padded CSR offsets stride (662 used)

using short8  = __attribute__((ext_vector_type(8))) short;
using float4v = __attribute__((ext_vector_type(4))) float;

__device__ __forceinline__ unsigned short f2bf(float x) {
    unsigned int u = __float_as_uint(x);
    unsigned int r = u + 0x7FFFu + ((u >> 16) & 1u);
    return (unsigned short)(r >> 16);
}
__device__ __forceinline__ float bf2f(unsigned short h) {
    return __uint_as_float(((unsigned int)h) << 16);
}

// ---------------------------------------------------------------------------
// Kernel 0: build bf16 hi/lo B-fragments of W1/W2 in MFMA B-operand layout:
//   flat = ((kstep*4 + otile)*64 + lane)*8 + j
//   B[k][n] with k = kstep*32 + (lane>>4)*8 + j, n = otile*16 + (lane&15)
// Also zeroes attention partials.
// ---------------------------------------------------------------------------
__global__ __launch_bounds__(256) void wtrans(
    const float* __restrict__ W1, const float* __restrict__ W2,
    unsigned short* __restrict__ Wb1h, unsigned short* __restrict__ Wb1l,
    unsigned short* __restrict__ Wb2h, unsigned short* __restrict__ Wb2l,
    float* __restrict__ partials)
{
    int i = blockIdx.x*256 + threadIdx.x;     // 0..20479 elements
    if (i < 20480) {
        int j    = i & 7;
        int lane = (i >> 3) & 63;
        int ot   = (i >> 9) & 3;
        int ks   = i >> 11;
        int k = ks*32 + (lane >> 4)*8 + j;
        int o = ot*16 + (lane & 15);
        float w1 = W1[o*320 + k];
        float w2 = W2[o*320 + k];
        unsigned short h1 = f2bf(w1); Wb1h[i] = h1; Wb1l[i] = f2bf(w1 - bf2f(h1));
        unsigned short h2 = f2bf(w2); Wb2h[i] = h2; Wb2l[i] = f2bf(w2 - bf2f(h2));
    }
    if (blockIdx.x == 0) {
        for (int j2 = threadIdx.x; j2 < 1024; j2 += 256) partials[j2] = 0.f;
    }
}

// ---------------------------------------------------------------------------
// Kernel 1: per-(graph,matrix) counting sort -> CSR. LDS-light: pairs scatter
// directly to global (absorbed by L2).
// ---------------------------------------------------------------------------
__global__ __launch_bounds__(256) void csr_build(
    const int* __restrict__ rG, const int* __restrict__ cG, const float* __restrict__ vG,
    const int* __restrict__ rB, const int* __restrict__ cB, const float* __restrict__ vB,
    const int* __restrict__ r1, const int* __restrict__ c1, const float* __restrict__ v1,
    const int* __restrict__ r2, const int* __restrict__ c2, const float* __restrict__ v2,
    int* __restrict__ offs_out, int2* __restrict__ pairs_out)
{
    __shared__ int scount[N_NODES];
    __shared__ int soffs[N_NODES+1];
    __shared__ int scursor[N_NODES];
    __shared__ int spart[256];

    int bid = blockIdx.x;
    int g = bid & 127;
    int m = bid >> 7;
    const int*   rows = (m==0)?rG:(m==1)?rB:(m==2)?r1:r2;
    const int*   cols = (m==0)?cG:(m==1)?cB:(m==2)?c1:c2;
    const float* vals = (m==0)?vG:(m==1)?vB:(m==2)?v1:v2;

    int tid = threadIdx.x;
    int ebase = g*EPG;
    int gbase = g*N_NODES;
    int seg = m*N_GRAPH + g;

    for (int i = tid; i < N_NODES; i += 256) scount[i] = 0;
    __syncthreads();
    for (int i = tid; i < EPG; i += 256)
        atomicAdd(&scount[rows[ebase+i] - gbase], 1);
    __syncthreads();

    int c0 = tid*3;
    int ps = 0;
    #pragma unroll
    for (int j = 0; j < 3; ++j) { int i = c0+j; if (i < N_NODES) ps += scount[i]; }
    spart[tid] = ps;
    __syncthreads();
    if (tid == 0) {
        int run = 0;
        for (int i = 0; i < 256; ++i) { int t = spart[i]; spart[i] = run; run += t; }
        soffs[N_NODES] = EPG;
    }
    __syncthreads();
    int run = spart[tid];
    #pragma unroll
    for (int j = 0; j < 3; ++j) {
        int i = c0+j;
        if (i < N_NODES) { soffs[i] = run; scursor[i] = run; run += scount[i]; }
    }
    __syncthreads();

    for (int i = tid; i <= N_NODES; i += 256)
        offs_out[(size_t)seg*OSTR + i] = soffs[i];

    int2* po = pairs_out + (size_t)seg*EPG;
    for (int i = tid; i < EPG; i += 256) {
        int r = rows[ebase+i] - gbase;
        int pos = atomicAdd(&scursor[r], 1);
        po[pos] = make_int2(cols[ebase+i], __float_as_int(vals[ebase+i]));
    }
}

// ---------------------------------------------------------------------------
__device__ __forceinline__ void node_math(
    float ev, float fv, float gd, float bd, float pd, float qd,
    float eGv, float fGv, float eBv, float fBv,
    float& e3v, float& nev, float& f3v, float& nfv)
{
    float invb = 1.0f/(ev*ev + fv*fv + 0.1f);
    float alpha = (pd*ev + qd*fv)*invb - eGv - fBv;
    float beta  = (qd*ev - pd*fv)*invb + fGv + eBv;
    float invg = 1.0f/(gd*gd + bd*bd);
    e3v = (alpha*gd + beta*bd)*invg;
    f3v = (beta*gd - alpha*bd)*invg;
    float bb1 = eGv - fBv, bb2 = fGv + eBv;
    float vv = ev*ev + fv*fv;
    float P_ = pd - vv*gd, Q_ = qd + vv*bd;
    nev = (P_*bb1 + Q_*bb2)*invg;
    nfv = (P_*bb2 - Q_*bb1)*invg;
}

// ---------------------------------------------------------------------------
// Kernel 2: one wave per node; chunked two-phase prefetch gather over all 4
// matrices + node math + attention partials. XCD-swizzled block mapping.
// ---------------------------------------------------------------------------
__global__ __launch_bounds__(256) void spmm_fused(
    const float* __restrict__ e, const float* __restrict__ f,
    const float* __restrict__ Gd, const float* __restrict__ Bd,
    const float* __restrict__ Pd, const float* __restrict__ Qd,
    const float* __restrict__ w_ae, const float* __restrict__ w_af,
    const int* __restrict__ offs, const int2* __restrict__ pairs,
    float* __restrict__ arrs, float* __restrict__ partials)
{
    int tid = threadIdx.x, lane = tid & 63, wv = tid >> 6;
    int bid = blockIdx.x;
    // XCD swizzle: consecutive-node block groups land on one XCD (bid%8 = XCD)
    int nb = (bid & 7) * (NTOT/4/8) + (bid >> 3);
    int node = nb*4 + wv;
    int g = node / N_NODES;
    int r = node - g*N_NODES;
    size_t idx = (size_t)node*FDIM + lane;

    // preload all 8 CSR offsets (independent loads, one latency)
    int s_[4], t_[4];
    #pragma unroll
    for (int m = 0; m < 4; ++m) {
        const int* po = offs + (size_t)(m*N_GRAPH + g)*OSTR + r;
        s_[m] = po[0];
        t_[m] = po[1];
    }

    float acc[8];
    #pragma unroll
    for (int j = 0; j < 8; ++j) acc[j] = 0.f;

    #pragma unroll
    for (int m = 0; m < 4; ++m) {
        const int2* pp = pairs + (size_t)(m*N_GRAPH + g)*EPG;
        int s = s_[m], t = t_[m];
        for (int base = s; base < t; base += 8) {
            // phase 1: 8 independent pair loads (clamped tail)
            int2 pb[8];
            #pragma unroll
            for (int j = 0; j < 8; ++j) {
                int kk = (base + j < t) ? (base + j) : (t - 1);
                pb[j] = pp[kk];
            }
            // phase 2: 16 independent gather loads
            float ev[8], fv[8];
            #pragma unroll
            for (int j = 0; j < 8; ++j) {
                size_t ci = (size_t)pb[j].x*FDIM + lane;
                ev[j] = e[ci];
                fv[j] = f[ci];
            }
            // phase 3: FMAs (zero the clamped tail)
            #pragma unroll
            for (int j = 0; j < 8; ++j) {
                float v = (base + j < t) ? __int_as_float(pb[j].y) : 0.f;
                acc[2*m]   = fmaf(v, ev[j], acc[2*m]);
                acc[2*m+1] = fmaf(v, fv[j], acc[2*m+1]);
            }
        }
    }

    float ev0 = e[idx], fv0 = f[idx];
    float gd = Gd[node], bd = Bd[node], pd = Pd[node], qd = Qd[node];
    float e3v, nev, f3v, nfv;
    node_math(ev0, fv0, gd, bd, pd, qd, acc[0], acc[1], acc[2], acc[3],
              e3v, nev, f3v, nfv);

    arrs[0*NF + idx] = e3v;
    arrs[1*NF + idx] = nev;
    arrs[2*NF + idx] = acc[4];   // e1
    arrs[3*NF + idx] = acc[6];   // e2
    arrs[4*NF + idx] = f3v;
    arrs[5*NF + idx] = nfv;
    arrs[6*NF + idx] = acc[5];   // f1
    arrs[7*NF + idx] = acc[7];   // f2

    float wa = w_ae[lane], wf = w_af[lane];
    float pa[8];
    pa[0] = e3v*wa; pa[1] = nev*wa; pa[2] = acc[4]*wa; pa[3] = acc[6]*wa;
    pa[4] = f3v*wf; pa[5] = nfv*wf; pa[6] = acc[5]*wf; pa[7] = acc[7]*wf;
    #pragma unroll
    for (int j = 0; j < 8; ++j) {
        float v = pa[j];
        for (int off = 32; off > 0; off >>= 1) v += __shfl_down(v, off);
        if (lane == 0) atomicAdd(&partials[g*8 + j], v);
    }
}

// ---------------------------------------------------------------------------
// Kernel 3: finalize attention weights
// ---------------------------------------------------------------------------
__global__ void attn_final(const float* __restrict__ partials,
                           const float* __restrict__ b_ae, const float* __restrict__ b_af,
                           float* __restrict__ att)
{
    int g = threadIdx.x;
    if (g >= N_GRAPH) return;
    float ae[4], af[4], se = 1e-4f, sf = 1e-4f;
    float bae = b_ae[0], baf = b_af[0];
    #pragma unroll
    for (int j = 0; j < 4; ++j) {
        float x = partials[g*8 + j]*(1.0f/N_NODES) + bae;
        ae[j] = 1.0f/(1.0f + expf(-x)); se += ae[j];
        float y = partials[g*8 + 4 + j]*(1.0f/N_NODES) + baf;
        af[j] = 1.0f/(1.0f + expf(-y)); sf += af[j];
    }
    #pragma unroll
    for (int j = 0; j < 4; ++j) {
        att[g*8 + j]     = ae[j]/se;
        att[g*8 + 4 + j] = af[j]/sf;
    }
}

// ---------------------------------------------------------------------------
// Kernel 4: cat build in LDS (f32) + MFMA GEMM (split-bf16 hi/lo, f32-grade
// precision) + tanh. 16 nodes/block, 4 waves = 4 o-tiles of 16.
// ---------------------------------------------------------------------------
#define STR 324
__global__ __launch_bounds__(256) void final_fused(
    const float* __restrict__ e, const float* __restrict__ f,
    const float* __restrict__ arrs, const float* __restrict__ att,
    const unsigned short* __restrict__ Wb1h, const unsigned short* __restrict__ Wb1l,
    const unsigned short* __restrict__ Wb2h, const unsigned short* __restrict__ Wb2l,
    const float* __restrict__ bv1, const float* __restrict__ bv2,
    float* __restrict__ out)
{
    __shared__ __align__(16) float cat_e[16*STR];
    __shared__ __align__(16) float cat_f[16*STR];

    int tid = threadIdx.x, lane = tid & 63, chunk = tid >> 6;
    int node0 = blockIdx.x * 16;

    #pragma unroll
    for (int round = 0; round < 4; ++round) {
        int ni = round*4 + chunk;
        int node = node0 + ni;
        int g = node / N_NODES;
        size_t idx = (size_t)node*FDIM + lane;
        float* ce = &cat_e[ni*STR];
        float* cf = &cat_f[ni*STR];
        ce[lane]     = arrs[0*NF + idx]*att[g*8+0];
        ce[64+lane]  = arrs[1*NF + idx]*att[g*8+1];
        ce[128+lane] = arrs[2*NF + idx]*att[g*8+2];
        ce[192+lane] = arrs[3*NF + idx]*att[g*8+3];
        ce[256+lane] = e[idx];
        cf[lane]     = arrs[4*NF + idx]*att[g*8+4];
        cf[64+lane]  = arrs[5*NF + idx]*att[g*8+5];
        cf[128+lane] = arrs[6*NF + idx]*att[g*8+6];
        cf[192+lane] = arrs[7*NF + idx]*att[g*8+7];
        cf[256+lane] = f[idx];
    }
    __syncthreads();

    // MFMA: A = cat[16 x 320], B = W^T[320 x 16-o-tile], C[16 x 16] per wave.
    // A-frag: lane holds A[m=lane&15][k = kstep*32 + (lane>>4)*8 + j], j=0..7
    // C-frag: col(o16) = lane&15, row(node) = (lane>>4)*4 + reg
    float4v acc_e = {0.f, 0.f, 0.f, 0.f};
    float4v acc_f = {0.f, 0.f, 0.f, 0.f};
    int m16 = lane & 15, quad = lane >> 4;

    for (int ks = 0; ks < 10; ++ks) {
        const float* ar = &cat_e[m16*STR + ks*32 + quad*8];
        float4 a0 = *(const float4*)ar;
        float4 a1 = *(const float4*)(ar + 4);
        const float* br = &cat_f[m16*STR + ks*32 + quad*8];
        float4 c0 = *(const float4*)br;
        float4 c1 = *(const float4*)(br + 4);

        float av[8] = {a0.x,a0.y,a0.z,a0.w,a1.x,a1.y,a1.z,a1.w};
        float cv[8] = {c0.x,c0.y,c0.z,c0.w,c1.x,c1.y,c1.z,c1.w};
        short8 ah, al, ch, cl;
        #pragma unroll
        for (int j = 0; j < 8; ++j) {
            unsigned short h = f2bf(av[j]);
            ah[j] = (short)h; al[j] = (short)f2bf(av[j] - bf2f(h));
            unsigned short h2 = f2bf(cv[j]);
            ch[j] = (short)h2; cl[j] = (short)f2bf(cv[j] - bf2f(h2));
        }

        size_t boff = (size_t)((ks*4 + chunk)*64 + lane)*8;
        short8 b1h = *(const short8*)(Wb1h + boff);
        short8 b1l = *(const short8*)(Wb1l + boff);
        short8 b2h = *(const short8*)(Wb2h + boff);
        short8 b2l = *(const short8*)(Wb2l + boff);

        acc_e = __builtin_amdgcn_mfma_f32_16x16x32_bf16(ah, b1h, acc_e, 0, 0, 0);
        acc_e = __builtin_amdgcn_mfma_f32_16x16x32_bf16(al, b1h, acc_e, 0, 0, 0);
        acc_e = __builtin_amdgcn_mfma_f32_16x16x32_bf16(ah, b1l, acc_e, 0, 0, 0);
        acc_f = __builtin_amdgcn_mfma_f32_16x16x32_bf16(ch, b2h, acc_f, 0, 0, 0);
        acc_f = __builtin_amdgcn_mfma_f32_16x16x32_bf16(cl, b2h, acc_f, 0, 0, 0);
        acc_f = __builtin_amdgcn_mfma_f32_16x16x32_bf16(ch, b2l, acc_f, 0, 0, 0);
    }

    int o = chunk*16 + m16;
    float be = bv1[o], bf = bv2[o];
    #pragma unroll
    for (int reg = 0; reg < 4; ++reg) {
        int node = node0 + quad*4 + reg;
        out[(size_t)node*FDIM + o]      = tanhf(acc_e[reg] + be);
        out[NF + (size_t)node*FDIM + o] = tanhf(acc_f[reg] + bf);
    }
}

// ---------------------------------------------------------------------------
extern "C" void kernel_launch(void* const* d_in, const int* in_sizes, int n_in,
                              void* d_out, int out_size, void* d_ws, size_t ws_size,
                              hipStream_t stream) {
    (void)in_sizes; (void)n_in; (void)out_size; (void)ws_size;
    const float* e     = (const float*)d_in[0];
    const float* f     = (const float*)d_in[1];
    const int*   rowsG = (const int*)d_in[2];
    const int*   colsG = (const int*)d_in[3];
    const float* valsG = (const float*)d_in[4];
    const int*   rowsB = (const int*)d_in[5];
    const int*   colsB = (const int*)d_in[6];
    const float* valsB = (const float*)d_in[7];
    const int*   rows1 = (const int*)d_in[8];
    const int*   cols1 = (const int*)d_in[9];
    const float* vals1 = (const float*)d_in[10];
    const int*   rows2 = (const int*)d_in[11];
    const int*   cols2 = (const int*)d_in[12];
    const float* vals2 = (const float*)d_in[13];
    const float* G_d   = (const float*)d_in[14];
    const float* B_d   = (const float*)d_in[15];
    const float* Pd    = (const float*)d_in[16];
    const float* Qd    = (const float*)d_in[17];
    const float* W1    = (const float*)d_in[18];
    const float* b1    = (const float*)d_in[19];
    const float* W2    = (const float*)d_in[20];
    const float* b2    = (const float*)d_in[21];
    const float* w_ae  = (const float*)d_in[22];
    const float* b_ae  = (const float*)d_in[23];
    const float* w_af  = (const float*)d_in[24];
    const float* b_af  = (const float*)d_in[25];

    float* ws       = (float*)d_ws;
    float* arrs     = ws;                          // 8*NF
    float* partials = ws + 8*NF;                   // 1024
    float* att      = partials + 1024;             // 1024
    unsigned short* Wb1h = (unsigned short*)(att + 1024);  // 20480 each
    unsigned short* Wb1l = Wb1h + 20480;
    unsigned short* Wb2h = Wb1l + 20480;
    unsigned short* Wb2l = Wb2h + 20480;
    int*   offs     = (int*)(Wb2l + 20480);        // 512*OSTR ints
    int2*  pairs    = (int2*)(offs + 512*OSTR);    // 512*EPG int2

    wtrans<<<dim3(80), dim3(256), 0, stream>>>(W1, W2, Wb1h, Wb1l, Wb2h, Wb2l, partials);

    csr_build<<<dim3(512), dim3(256), 0, stream>>>(
        rowsG, colsG, valsG, rowsB, colsB, valsB,
        rows1, cols1, vals1, rows2, cols2, vals2, offs, pairs);

    spmm_fused<<<dim3(NTOT/4), dim3(256), 0, stream>>>(
        e, f, G_d, B_d, Pd, Qd, w_ae, w_af, offs, pairs, arrs, partials);

    attn_final<<<dim3(1), dim3(128), 0, stream>>>(partials, b_ae, b_af, att);

    final_fused<<<dim3(NTOT/16), dim3(256), 0, stream>>>(
        e, f, arrs, att, Wb1h, Wb1l, Wb2h, Wb2l, b1, b2, (float*)d_out);
}